// Round 11
// baseline (329.385 us; speedup 1.0000x reference)
//
#include <hip/hip_runtime.h>
#include <hip/hip_bf16.h>

typedef __attribute__((ext_vector_type(4))) float f32x4;
typedef __attribute__((ext_vector_type(8))) short bf16x8;

#define IN_DIM 4096
#define OUT_DIM 4096
#define MROWS 8192   // B*S = 4*2048
#define NFREQ 8
#define TWO_PI 6.283185307179586f

// f32 -> bf16 bits, round-to-nearest-even
__device__ __forceinline__ unsigned int f2bf(float f) {
    union { float f; unsigned int u; } a;
    a.f = f;
    unsigned int u = a.u;
    u += 0x7fffu + ((u >> 16) & 1u);
    return u >> 16;
}

// ---------------------------------------------------------------------------
// Fused prep kernel.
//  blocks [0, 4096):      dora rows — W_dora(bf16) = m*(W+irfft2(pad(delta)))/(||row||+eps)
//  blocks [4096, 20480):  x f32 -> bf16 cvt
// ---------------------------------------------------------------------------
#define ROT_C 0.9999988234517019f
#define ROT_S 0.0015339801862847655f

__global__ __launch_bounds__(256) void prep_kernel(
    const float* __restrict__ x,
    const float* __restrict__ W,
    const float* __restrict__ dre,
    const float* __restrict__ dimg,
    const float* __restrict__ mrow,
    unsigned short* __restrict__ Wd,
    unsigned short* __restrict__ xb)
{
    const int t = threadIdx.x;

    if (blockIdx.x >= OUT_DIM) {
        // ---- cvt branch ----
        const size_t idx = (size_t)(blockIdx.x - OUT_DIM) * 256 + t;
        const f32x4* p = (const f32x4*)(x + idx * 8);
        const f32x4 a = p[0], b = p[1];
        uint4 o;
        o.x = f2bf(a[0]) | (f2bf(a[1]) << 16);
        o.y = f2bf(a[2]) | (f2bf(a[3]) << 16);
        o.z = f2bf(b[0]) | (f2bf(b[1]) << 16);
        o.w = f2bf(b[2]) | (f2bf(b[3]) << 16);
        *(uint4*)(xb + idx * 8) = o;
        return;
    }

    // ---- dora branch ----
    const int o = blockIdx.x;

    float P[NFREQ], Q[NFREQ];
#pragma unroll
    for (int w = 0; w < NFREQ; ++w) { P[w] = 0.f; Q[w] = 0.f; }
#pragma unroll
    for (int h = 0; h < NFREQ; ++h) {
        const float th = (TWO_PI / 4096.0f) * (float)((h * o) & 4095);
        const float sh = __sinf(th), ch = __cosf(th);
#pragma unroll
        for (int w = 0; w < NFREQ; ++w) {
            const float A = 2.0f * dre[h * NFREQ + w];
            const float B = 2.0f * dimg[h * NFREQ + w];
            P[w] += A * ch - B * sh;
            Q[w] += A * sh + B * ch;
        }
    }
#pragma unroll
    for (int w = 0; w < NFREQ; ++w) {
        const float c = (w == 0 ? 1.0f : 2.0f) * (1.0f / 4096.0f);
        P[w] *= c; Q[w] *= c;
    }

    const int i0 = t * 16;
    const f32x4* wrow = (const f32x4*)(W + (size_t)o * IN_DIM + i0);
    float vals[16];
    float ss = 0.0f;

    const float beta0 = (TWO_PI / 4096.0f) * (float)i0;
    float cb = __cosf(beta0), sb = __sinf(beta0);

#pragma unroll
    for (int q = 0; q < 4; ++q) {
        const f32x4 wv = wrow[q];
#pragma unroll
        for (int j = 0; j < 4; ++j) {
            float cw = cb, sw = sb;
            float d = P[0] + P[1] * cw - Q[1] * sw;
#pragma unroll
            for (int w = 2; w < NFREQ; ++w) {
                const float cn = cw * cb - sw * sb;
                sw = sw * cb + cw * sb;
                cw = cn;
                d += P[w] * cw - Q[w] * sw;
            }
            const float v = wv[j] + d;
            vals[q * 4 + j] = v;
            ss += v * v;
            const float cbn = cb * ROT_C - sb * ROT_S;
            sb = sb * ROT_C + cb * ROT_S;
            cb = cbn;
        }
    }

#pragma unroll
    for (int off = 32; off > 0; off >>= 1)
        ss += __shfl_down(ss, off, 64);
    __shared__ float red[4];
    if ((t & 63) == 0) red[t >> 6] = ss;
    __syncthreads();
    const float n2 = red[0] + red[1] + red[2] + red[3];
    const float scale = mrow[o] / (sqrtf(n2) + 1e-8f);

    unsigned int wds[8];
#pragma unroll
    for (int k = 0; k < 8; ++k)
        wds[k] = f2bf(vals[2 * k] * scale) | (f2bf(vals[2 * k + 1] * scale) << 16);
    uint4* dst = (uint4*)(Wd + (size_t)o * IN_DIM + i0);
    dst[0] = make_uint4(wds[0], wds[1], wds[2], wds[3]);
    dst[1] = make_uint4(wds[4], wds[5], wds[6], wds[7]);
}

// ---------------------------------------------------------------------------
// 128x256-tile bf16 GEMM, BK=32, 4 waves (2m x 2n), 48 KiB LDS -> 2 blocks/CU.
//
// Occupancy experiment: per-CU traffic and per-SIMD MFMA identical to the R7
// 256x256/8-wave kernel, but two INDEPENDENT 4-wave blocks per CU interleave
// their barrier stalls (R7 runs 1 block/CU: both waves on a SIMD rendezvous
// at the same barrier and the SIMD idles ~28% of cycles).
//
// LDS (48 KiB): A[2][128][32] bf16 @0 (buf stride 8192),
//               B[2][256][32] bf16 @16384 (buf stride 16384).
// Swizzle (64 B rows, 4x16B chunks): slot (row, c) holds global chunk
// c ^ (row&3). DMA dest is linear, so the SOURCE column is pre-swizzled:
// lane l covers row (l>>2) (mod 16-group), chunk l&3 -> source chunk
// (l&3)^((l>>2)&3). Reads fetch chunk fq^(fr&3). Full-wave b128: 8 lanes
// per 16B-column, uniform over 32 banks = 0 conflicts (same invariant as
// R7's 128B-row version, re-derived for 64B rows).
//
// Per-wave: 64x128 output, acc[4][8] f32x4 (128 regs, same as R7).
// Per K-tile (32): 12 ds_read_b128 (4 A + 8 B), 32 MFMA, 6 gloads.
//
// Schedule per K-tile t (buf b=t&1), 2 barriers/tile:
//   P1: rd a(4)+bb(8) | STAGE B(t+1)->b^1 (4 gl) | prio1 MFMA nf0-3 prio0
//       | lgkm0 | SBAR   (seals ALL tile-t reads)
//   P2: STAGE A(t+2)->b (2 gl) | prio1 MFMA nf4-7 prio0
//       | vmcnt(st2?2:0) | SBAR  (tile boundary)
//
// WAR ledger: B(t+1)->b^1 @P1: b^1 B reads were in tile t-1's P1, sealed by
//   its P1-end SBAR. A(t+2)->b @P2: all buf-b reads sealed by P1-end SBAR.
// vmcnt ledger (per wave): enter tile t with A(t+1)=2 outstanding.
//   P1 +4 (B t+1) = 6; P2 +2 (A t+2) = 8; vmcnt(2) drains the oldest 6
//   = exactly A(t+1)+B(t+1), leaving A(t+2). Tail t=NT-2: vmcnt(0).
// ---------------------------------------------------------------------------

#define GLOAD(src, ldsoff)                                                    \
    __builtin_amdgcn_global_load_lds(                                         \
        (const __attribute__((address_space(1))) void*)(src),                 \
        (__attribute__((address_space(3))) void*)(smem + (ldsoff)), 16, 0, 0)

#define SBAR      asm volatile("s_barrier" ::: "memory")
#define WAITLGKM0 asm volatile("s_waitcnt lgkmcnt(0)" ::: "memory")

__global__ __launch_bounds__(256, 2) void gemm_k32_kernel(
    const unsigned short* __restrict__ Xb,
    const unsigned short* __restrict__ Wd,
    const float* __restrict__ bias,
    float* __restrict__ out)
{
    __shared__ __align__(1024) unsigned char smem[49152];

    const int tid = threadIdx.x;
    const int wid = tid >> 6, lane = tid & 63;
    const int wr = wid >> 1, wc = wid & 1;        // 2M x 2N waves
    const int fr = lane & 15, fq = lane >> 4;     // fragment row / k-chunk

    // paired-tn XCD swizzle (bijective: 1024 blocks, 8 XCDs)
    const int bid = blockIdx.x;
    const int xcd = bid & 7;
    const int u = bid >> 3;                // [0,128) per XCD
    const int tm = u >> 1;                 // 0..63
    const int tn = 2 * xcd + (u & 1);      // 0..15
    const int m0 = tm * 128, n0 = tn * 256;

    // ---- staging coords: pre-swizzled global source, linear LDS dest ----
    const int srow = wid * 16 + (lane >> 2);                  // row within 64-row gload
    const int scc = ((lane & 3) ^ ((lane >> 2) & 3)) * 8;     // swizzled col (elems)
    const unsigned short* aS = Xb + (size_t)(m0 + srow) * IN_DIM + scc;
    const unsigned short* bS = Wd + (size_t)(n0 + srow) * IN_DIM + scc;
    const int sdst = wid * 1024;                              // + g*4096

    // ---- ds_read lane bases (swizzled chunk = fq ^ (fr&3)) ----
    const int cb4 = ((fq ^ (fr & 3)) * 16);
    const int aB = (wr * 64 + fr) * 64 + cb4;        // + b*8192  + mf*1024
    const int bB = (wc * 128 + fr) * 64 + cb4;       // + 16384 + b*16384 + nf*1024

    auto STAGEA = [&](int buf, int tt) {
#pragma unroll
        for (int g = 0; g < 2; ++g)
            GLOAD(aS + (size_t)(g * 64) * IN_DIM + (size_t)tt * 32,
                  buf * 8192 + g * 4096 + sdst);
    };
    auto STAGEB = [&](int buf, int tt) {
#pragma unroll
        for (int g = 0; g < 4; ++g)
            GLOAD(bS + (size_t)(g * 64) * IN_DIM + (size_t)tt * 32,
                  16384 + buf * 16384 + g * 4096 + sdst);
    };

    f32x4 acc[4][8] = {};
    bf16x8 af[4], bf[8];

    // ---- prologue: A(0), B(0), A(1). Drain A(0)+B(0) (6): vmcnt(2). ----
    STAGEA(0, 0);
    STAGEB(0, 0);
    STAGEA(1, 1);
    asm volatile("s_waitcnt vmcnt(2)" ::: "memory");
    SBAR;

    const int NT2 = IN_DIM / 32;   // 128 K-tiles
    for (int t = 0; t < NT2; ++t) {
        const int b = t & 1;
        const int boA = b * 8192;
        const int boB = 16384 + b * 16384;
        const bool st1 = (t + 1 < NT2);   // stage B(t+1)
        const bool st2 = (t + 2 < NT2);   // stage A(t+2)

        // ---------------- P1: MFMA nf0-3 ----------------
#pragma unroll
        for (int mf = 0; mf < 4; ++mf)
            af[mf] = *(const bf16x8*)(smem + boA + aB + mf * 1024);
#pragma unroll
        for (int nf = 0; nf < 8; ++nf)
            bf[nf] = *(const bf16x8*)(smem + boB + bB + nf * 1024);
        if (st1) STAGEB(b ^ 1, t + 1);
        __builtin_amdgcn_s_setprio(1);
#pragma unroll
        for (int mf = 0; mf < 4; ++mf)
#pragma unroll
            for (int nf = 0; nf < 4; ++nf)
                acc[mf][nf] = __builtin_amdgcn_mfma_f32_16x16x32_bf16(
                    af[mf], bf[nf], acc[mf][nf], 0, 0, 0);
        __builtin_amdgcn_s_setprio(0);
        WAITLGKM0;   // all tile-t fragment reads retired
        SBAR;        // seals tile-t reads -> P2's A-stage may overwrite buf b

        // ---------------- P2: MFMA nf4-7 ----------------
        if (st2) STAGEA(b, t + 2);
        __builtin_amdgcn_s_setprio(1);
#pragma unroll
        for (int mf = 0; mf < 4; ++mf)
#pragma unroll
            for (int nf = 4; nf < 8; ++nf)
                acc[mf][nf] = __builtin_amdgcn_mfma_f32_16x16x32_bf16(
                    af[mf], bf[nf], acc[mf][nf], 0, 0, 0);
        __builtin_amdgcn_s_setprio(0);
        if (st2) {
            asm volatile("s_waitcnt vmcnt(2)" ::: "memory");
        } else {
            asm volatile("s_waitcnt vmcnt(0)" ::: "memory");
        }
        SBAR;   // tile boundary: tile t+1 fully staged & visible
    }

    // ---- epilogue: bias add + f32 store ----
    // C/D: col = fr, row = fq*4 + reg
#pragma unroll
    for (int nf = 0; nf < 8; ++nf) {
        const int col = n0 + wc * 128 + nf * 16 + fr;
        const float bv = bias[col];
#pragma unroll
        for (int mf = 0; mf < 4; ++mf) {
            const int row = m0 + wr * 64 + mf * 16 + fq * 4;
            float* op = out + (size_t)row * OUT_DIM + col;
            op[0 * OUT_DIM] = acc[mf][nf][0] + bv;
            op[1 * OUT_DIM] = acc[mf][nf][1] + bv;
            op[2 * OUT_DIM] = acc[mf][nf][2] + bv;
            op[3 * OUT_DIM] = acc[mf][nf][3] + bv;
        }
    }
}

// ---------------------------------------------------------------------------
// Fallback GEMM (128x128, reg-staged f32 A) — only if ws too small for Xb.
// ---------------------------------------------------------------------------
__global__ __launch_bounds__(256) void gemm_fallback(
    const float* __restrict__ Xf,
    const unsigned short* __restrict__ Wd,
    const float* __restrict__ bias,
    float* __restrict__ out)
{
    __shared__ unsigned short As[2][128 * 32];
    __shared__ unsigned short Bs[2][128 * 32];

    const int t = threadIdx.x;
    const int wid = t >> 6, lane = t & 63;
    const int wr = wid >> 1, wc = wid & 1;
    const int m0 = blockIdx.x * 128, n0 = blockIdx.y * 128;
    const int fr = lane & 15, fq = lane >> 4;

    f32x4 acc[4][4] = {};

    const int srow = wid * 16 + (lane >> 2);
    const int scol = (lane & 3) * 8;
    const unsigned short* bsrc0 = Wd + (size_t)(n0 + srow) * IN_DIM + scol;
    const unsigned short* bsrc1 = bsrc0 + (size_t)64 * IN_DIM;
    const int lds_off = wid * 512;

    const int ar = t >> 1;
    const int ak = (t & 1) * 16;
    const float* afp = Xf + (size_t)(m0 + ar) * IN_DIM + ak;
    const int a_lds_off = ar * 32 + ak;

    auto stageB = [&](unsigned short* ldsbase, int kt) {
        __builtin_amdgcn_global_load_lds(
            (const __attribute__((address_space(1))) void*)(bsrc0 + kt * 32),
            (__attribute__((address_space(3))) void*)(ldsbase + lds_off), 16, 0, 0);
        __builtin_amdgcn_global_load_lds(
            (const __attribute__((address_space(1))) void*)(bsrc1 + kt * 32),
            (__attribute__((address_space(3))) void*)(ldsbase + 2048 + lds_off), 16, 0, 0);
    };
    auto writeA = [&](int buf, const f32x4* v) {
        unsigned int w[8];
#pragma unroll
        for (int k = 0; k < 4; ++k) {
            w[2 * k]     = f2bf(v[k][0]) | (f2bf(v[k][1]) << 16);
            w[2 * k + 1] = f2bf(v[k][2]) | (f2bf(v[k][3]) << 16);
        }
        uint4* d = (uint4*)(&As[buf][a_lds_off]);
        d[0] = make_uint4(w[0], w[1], w[2], w[3]);
        d[1] = make_uint4(w[4], w[5], w[6], w[7]);
    };

    stageB(Bs[0], 0);
    {
        f32x4 av[4];
        const f32x4* ap = (const f32x4*)afp;
        av[0] = ap[0]; av[1] = ap[1]; av[2] = ap[2]; av[3] = ap[3];
        writeA(0, av);
    }
    __syncthreads();

    for (int kt = 0; kt < IN_DIM / 32; ++kt) {
        const int cur = kt & 1;
        const bool more = (kt + 1 < IN_DIM / 32);
        f32x4 nv[4];
        if (more) {
            const f32x4* ap = (const f32x4*)(afp + (size_t)(kt + 1) * 32);
            nv[0] = ap[0]; nv[1] = ap[1]; nv[2] = ap[2]; nv[3] = ap[3];
            stageB(Bs[cur ^ 1], kt + 1);
        }
        bf16x8 afrag[4], bfrag[4];
#pragma unroll
        for (int mf = 0; mf < 4; ++mf)
            afrag[mf] = *(const bf16x8*)(&As[cur][(wr * 64 + mf * 16 + fr) * 32 + fq * 8]);
#pragma unroll
        for (int nf = 0; nf < 4; ++nf)
            bfrag[nf] = *(const bf16x8*)(&Bs[cur][(wc * 64 + nf * 16 + fr) * 32 + fq * 8]);
#pragma unroll
        for (int mf = 0; mf < 4; ++mf)
#pragma unroll
            for (int nf = 0; nf < 4; ++nf)
                acc[mf][nf] = __builtin_amdgcn_mfma_f32_16x16x32_bf16(
                    afrag[mf], bfrag[nf], acc[mf][nf], 0, 0, 0);
        if (more) writeA(cur ^ 1, nv);
        __syncthreads();
    }

#pragma unroll
    for (int nf = 0; nf < 4; ++nf) {
        const int col = n0 + wc * 64 + nf * 16 + fr;
        const float bv = bias[col];
#pragma unroll
        for (int mf = 0; mf < 4; ++mf) {
            const int row = m0 + wr * 64 + mf * 16 + fq * 4;
            float* op = out + (size_t)row * OUT_DIM + col;
            op[0 * OUT_DIM] = acc[mf][nf][0] + bv;
            op[1 * OUT_DIM] = acc[mf][nf][1] + bv;
            op[2 * OUT_DIM] = acc[mf][nf][2] + bv;
            op[3 * OUT_DIM] = acc[mf][nf][3] + bv;
        }
    }
}

extern "C" void kernel_launch(void* const* d_in, const int* in_sizes, int n_in,
                              void* d_out, int out_size, void* d_ws, size_t ws_size,
                              hipStream_t stream) {
    const float* x    = (const float*)d_in[0];
    const float* W    = (const float*)d_in[1];
    const float* bias = (const float*)d_in[2];
    const float* dre  = (const float*)d_in[3];
    const float* dimg = (const float*)d_in[4];
    const float* mrow = (const float*)d_in[5];
    float* out = (float*)d_out;

    unsigned short* Wd = (unsigned short*)d_ws;
    const size_t WD_BYTES = (size_t)OUT_DIM * IN_DIM * 2;   // 32 MiB
    const size_t XB_BYTES = (size_t)MROWS * IN_DIM * 2;     // 64 MiB
    unsigned short* Xb = (unsigned short*)((char*)d_ws + WD_BYTES);
    const bool fast = ws_size >= WD_BYTES + XB_BYTES;

    if (fast) {
        const int cvt_blocks = (MROWS * (size_t)IN_DIM / 8) / 256;  // 16384
        prep_kernel<<<OUT_DIM + cvt_blocks, 256, 0, stream>>>(
            x, W, dre, dimg, mrow, Wd, Xb);
        gemm_k32_kernel<<<dim3((MROWS / 128) * (OUT_DIM / 256)), dim3(256), 0, stream>>>(
            Xb, Wd, bias, out);
    } else {
        prep_kernel<<<OUT_DIM, 256, 0, stream>>>(x, W, dre, dimg, mrow, Wd, Wd);
        dim3 grid(MROWS / 128, OUT_DIM / 128);
        gemm_fallback<<<grid, dim3(256), 0, stream>>>(x, Wd, bias, out);
    }
}

// Round 12
// 328.585 us; speedup vs baseline: 1.0024x; 1.0024x over previous
//
#include <hip/hip_runtime.h>
#include <hip/hip_bf16.h>

typedef __attribute__((ext_vector_type(4))) float f32x4;
typedef __attribute__((ext_vector_type(8))) short bf16x8;

#define IN_DIM 4096
#define OUT_DIM 4096
#define MROWS 8192   // B*S = 4*2048
#define NFREQ 8
#define TWO_PI 6.283185307179586f

// f32 -> bf16 bits, round-to-nearest-even
__device__ __forceinline__ unsigned int f2bf(float f) {
    union { float f; unsigned int u; } a;
    a.f = f;
    unsigned int u = a.u;
    u += 0x7fffu + ((u >> 16) & 1u);
    return u >> 16;
}

// ---------------------------------------------------------------------------
// Fused prep kernel.
//  blocks [0, 4096):      dora rows — W_dora(bf16) = m*(W+irfft2(pad(delta)))/(||row||+eps)
//  blocks [4096, 20480):  x f32 -> bf16 cvt
// ---------------------------------------------------------------------------
#define ROT_C 0.9999988234517019f
#define ROT_S 0.0015339801862847655f

__global__ __launch_bounds__(256) void prep_kernel(
    const float* __restrict__ x,
    const float* __restrict__ W,
    const float* __restrict__ dre,
    const float* __restrict__ dimg,
    const float* __restrict__ mrow,
    unsigned short* __restrict__ Wd,
    unsigned short* __restrict__ xb)
{
    const int t = threadIdx.x;

    if (blockIdx.x >= OUT_DIM) {
        // ---- cvt branch ----
        const size_t idx = (size_t)(blockIdx.x - OUT_DIM) * 256 + t;
        const f32x4* p = (const f32x4*)(x + idx * 8);
        const f32x4 a = p[0], b = p[1];
        uint4 o;
        o.x = f2bf(a[0]) | (f2bf(a[1]) << 16);
        o.y = f2bf(a[2]) | (f2bf(a[3]) << 16);
        o.z = f2bf(b[0]) | (f2bf(b[1]) << 16);
        o.w = f2bf(b[2]) | (f2bf(b[3]) << 16);
        *(uint4*)(xb + idx * 8) = o;
        return;
    }

    // ---- dora branch ----
    const int o = blockIdx.x;

    float P[NFREQ], Q[NFREQ];
#pragma unroll
    for (int w = 0; w < NFREQ; ++w) { P[w] = 0.f; Q[w] = 0.f; }
#pragma unroll
    for (int h = 0; h < NFREQ; ++h) {
        const float th = (TWO_PI / 4096.0f) * (float)((h * o) & 4095);
        const float sh = __sinf(th), ch = __cosf(th);
#pragma unroll
        for (int w = 0; w < NFREQ; ++w) {
            const float A = 2.0f * dre[h * NFREQ + w];
            const float B = 2.0f * dimg[h * NFREQ + w];
            P[w] += A * ch - B * sh;
            Q[w] += A * sh + B * ch;
        }
    }
#pragma unroll
    for (int w = 0; w < NFREQ; ++w) {
        const float c = (w == 0 ? 1.0f : 2.0f) * (1.0f / 4096.0f);
        P[w] *= c; Q[w] *= c;
    }

    const int i0 = t * 16;
    const f32x4* wrow = (const f32x4*)(W + (size_t)o * IN_DIM + i0);
    float vals[16];
    float ss = 0.0f;

    const float beta0 = (TWO_PI / 4096.0f) * (float)i0;
    float cb = __cosf(beta0), sb = __sinf(beta0);

#pragma unroll
    for (int q = 0; q < 4; ++q) {
        const f32x4 wv = wrow[q];
#pragma unroll
        for (int j = 0; j < 4; ++j) {
            float cw = cb, sw = sb;
            float d = P[0] + P[1] * cw - Q[1] * sw;
#pragma unroll
            for (int w = 2; w < NFREQ; ++w) {
                const float cn = cw * cb - sw * sb;
                sw = sw * cb + cw * sb;
                cw = cn;
                d += P[w] * cw - Q[w] * sw;
            }
            const float v = wv[j] + d;
            vals[q * 4 + j] = v;
            ss += v * v;
            const float cbn = cb * ROT_C - sb * ROT_S;
            sb = sb * ROT_C + cb * ROT_S;
            cb = cbn;
        }
    }

#pragma unroll
    for (int off = 32; off > 0; off >>= 1)
        ss += __shfl_down(ss, off, 64);
    __shared__ float red[4];
    if ((t & 63) == 0) red[t >> 6] = ss;
    __syncthreads();
    const float n2 = red[0] + red[1] + red[2] + red[3];
    const float scale = mrow[o] / (sqrtf(n2) + 1e-8f);

    unsigned int wds[8];
#pragma unroll
    for (int k = 0; k < 8; ++k)
        wds[k] = f2bf(vals[2 * k] * scale) | (f2bf(vals[2 * k + 1] * scale) << 16);
    uint4* dst = (uint4*)(Wd + (size_t)o * IN_DIM + i0);
    dst[0] = make_uint4(wds[0], wds[1], wds[2], wds[3]);
    dst[1] = make_uint4(wds[4], wds[5], wds[6], wds[7]);
}

// ---------------------------------------------------------------------------
// 128x256-tile bf16 GEMM, BK=32, 4 waves (2m x 2n), 48 KiB LDS -> 2 blocks/CU.
// R11 structure with the CORRECTED 64-B-row swizzle.
//
// Bank model (64-B rows, 4x16B chunks): a lane's b128 read touches banks
// 16*(row&1) + chunk*4 .. +3. For a quarter-wave (fq fixed, fr=0..15) to be
// conflict-free, each of the 8 (row-parity x chunk) groups must get exactly
// 2 lanes. (fr&1, (fr>>1)&3) enumerates all 8 combos exactly twice over
// fr=0..15, so the swizzle must be chunk ^= (row>>1)&3.
// R11's chunk ^= (row&3) aliased fr and fr+4 (same fr&3 AND same fr&1)
// -> 4-way conflict, measured 2.517e7. Corrected here:
//   staging source chunk: (lane&3) ^ ((lane>>3)&3)    [row_loc = lane>>2]
//   read chunk:           fq ^ ((fr>>1)&3)
// Row offsets added by mf/nf/wr/wc/wid are all multiples of 16 rows, which
// are == 0 (mod 4) after >>1, so lane-base formulas stay compile-time.
//
// LDS (48 KiB): A[2][128][32] bf16 @0 (buf stride 8192),
//               B[2][256][32] bf16 @16384 (buf stride 16384).
// Per-wave: 64x128 output, acc[4][8] f32x4. Per K-tile: 12 ds_read_b128,
// 32 MFMA, 6 gloads.
//
// Schedule per K-tile t (buf b=t&1), 2 barriers/tile:
//   P1: rd a(4)+bb(8) | STAGE B(t+1)->b^1 (4 gl) | prio1 MFMA nf0-3 prio0
//       | lgkm0 | SBAR   (seals ALL tile-t reads)
//   P2: STAGE A(t+2)->b (2 gl) | prio1 MFMA nf4-7 prio0
//       | vmcnt(st2?2:0) | SBAR  (tile boundary)
//
// WAR ledger: B(t+1)->b^1 @P1: b^1 B reads were in tile t-1's P1, sealed by
//   its P1-end SBAR. A(t+2)->b @P2: all buf-b reads sealed by P1-end SBAR.
// vmcnt ledger (per wave): enter tile t with A(t+1)=2 outstanding.
//   P1 +4 (B t+1) = 6; P2 +2 (A t+2) = 8; vmcnt(2) drains the oldest 6
//   = exactly A(t+1)+B(t+1), leaving A(t+2). Tail t=NT-2: vmcnt(0).
// ---------------------------------------------------------------------------

#define GLOAD(src, ldsoff)                                                    \
    __builtin_amdgcn_global_load_lds(                                         \
        (const __attribute__((address_space(1))) void*)(src),                 \
        (__attribute__((address_space(3))) void*)(smem + (ldsoff)), 16, 0, 0)

#define SBAR      asm volatile("s_barrier" ::: "memory")
#define WAITLGKM0 asm volatile("s_waitcnt lgkmcnt(0)" ::: "memory")

__global__ __launch_bounds__(256, 2) void gemm_k32_kernel(
    const unsigned short* __restrict__ Xb,
    const unsigned short* __restrict__ Wd,
    const float* __restrict__ bias,
    float* __restrict__ out)
{
    __shared__ __align__(1024) unsigned char smem[49152];

    const int tid = threadIdx.x;
    const int wid = tid >> 6, lane = tid & 63;
    const int wr = wid >> 1, wc = wid & 1;        // 2M x 2N waves
    const int fr = lane & 15, fq = lane >> 4;     // fragment row / k-chunk

    // paired-tn XCD swizzle (bijective: 1024 blocks, 8 XCDs)
    const int bid = blockIdx.x;
    const int xcd = bid & 7;
    const int u = bid >> 3;                // [0,128) per XCD
    const int tm = u >> 1;                 // 0..63
    const int tn = 2 * xcd + (u & 1);      // 0..15
    const int m0 = tm * 128, n0 = tn * 256;

    // ---- staging coords: pre-swizzled global source, linear LDS dest ----
    const int srow = wid * 16 + (lane >> 2);                  // row within 64-row gload
    const int scc = ((lane & 3) ^ ((lane >> 3) & 3)) * 8;     // swizzled col (elems)
    const unsigned short* aS = Xb + (size_t)(m0 + srow) * IN_DIM + scc;
    const unsigned short* bS = Wd + (size_t)(n0 + srow) * IN_DIM + scc;
    const int sdst = wid * 1024;                              // + g*4096

    // ---- ds_read lane bases (swizzled chunk = fq ^ ((fr>>1)&3)) ----
    const int cb4 = ((fq ^ ((fr >> 1) & 3)) * 16);
    const int aB = (wr * 64 + fr) * 64 + cb4;        // + b*8192  + mf*1024
    const int bB = (wc * 128 + fr) * 64 + cb4;       // + 16384 + b*16384 + nf*1024

    auto STAGEA = [&](int buf, int tt) {
#pragma unroll
        for (int g = 0; g < 2; ++g)
            GLOAD(aS + (size_t)(g * 64) * IN_DIM + (size_t)tt * 32,
                  buf * 8192 + g * 4096 + sdst);
    };
    auto STAGEB = [&](int buf, int tt) {
#pragma unroll
        for (int g = 0; g < 4; ++g)
            GLOAD(bS + (size_t)(g * 64) * IN_DIM + (size_t)tt * 32,
                  16384 + buf * 16384 + g * 4096 + sdst);
    };

    f32x4 acc[4][8] = {};
    bf16x8 af[4], bf[8];

    // ---- prologue: A(0), B(0), A(1). Drain A(0)+B(0) (6): vmcnt(2). ----
    STAGEA(0, 0);
    STAGEB(0, 0);
    STAGEA(1, 1);
    asm volatile("s_waitcnt vmcnt(2)" ::: "memory");
    SBAR;

    const int NT2 = IN_DIM / 32;   // 128 K-tiles
    for (int t = 0; t < NT2; ++t) {
        const int b = t & 1;
        const int boA = b * 8192;
        const int boB = 16384 + b * 16384;
        const bool st1 = (t + 1 < NT2);   // stage B(t+1)
        const bool st2 = (t + 2 < NT2);   // stage A(t+2)

        // ---------------- P1: MFMA nf0-3 ----------------
#pragma unroll
        for (int mf = 0; mf < 4; ++mf)
            af[mf] = *(const bf16x8*)(smem + boA + aB + mf * 1024);
#pragma unroll
        for (int nf = 0; nf < 8; ++nf)
            bf[nf] = *(const bf16x8*)(smem + boB + bB + nf * 1024);
        if (st1) STAGEB(b ^ 1, t + 1);
        __builtin_amdgcn_s_setprio(1);
#pragma unroll
        for (int mf = 0; mf < 4; ++mf)
#pragma unroll
            for (int nf = 0; nf < 4; ++nf)
                acc[mf][nf] = __builtin_amdgcn_mfma_f32_16x16x32_bf16(
                    af[mf], bf[nf], acc[mf][nf], 0, 0, 0);
        __builtin_amdgcn_s_setprio(0);
        WAITLGKM0;   // all tile-t fragment reads retired
        SBAR;        // seals tile-t reads -> P2's A-stage may overwrite buf b

        // ---------------- P2: MFMA nf4-7 ----------------
        if (st2) STAGEA(b, t + 2);
        __builtin_amdgcn_s_setprio(1);
#pragma unroll
        for (int mf = 0; mf < 4; ++mf)
#pragma unroll
            for (int nf = 4; nf < 8; ++nf)
                acc[mf][nf] = __builtin_amdgcn_mfma_f32_16x16x32_bf16(
                    af[mf], bf[nf], acc[mf][nf], 0, 0, 0);
        __builtin_amdgcn_s_setprio(0);
        if (st2) {
            asm volatile("s_waitcnt vmcnt(2)" ::: "memory");
        } else {
            asm volatile("s_waitcnt vmcnt(0)" ::: "memory");
        }
        SBAR;   // tile boundary: tile t+1 fully staged & visible
    }

    // ---- epilogue: bias add + f32 store ----
    // C/D: col = fr, row = fq*4 + reg
#pragma unroll
    for (int nf = 0; nf < 8; ++nf) {
        const int col = n0 + wc * 128 + nf * 16 + fr;
        const float bv = bias[col];
#pragma unroll
        for (int mf = 0; mf < 4; ++mf) {
            const int row = m0 + wr * 64 + mf * 16 + fq * 4;
            float* op = out + (size_t)row * OUT_DIM + col;
            op[0 * OUT_DIM] = acc[mf][nf][0] + bv;
            op[1 * OUT_DIM] = acc[mf][nf][1] + bv;
            op[2 * OUT_DIM] = acc[mf][nf][2] + bv;
            op[3 * OUT_DIM] = acc[mf][nf][3] + bv;
        }
    }
}

// ---------------------------------------------------------------------------
// Fallback GEMM (128x128, reg-staged f32 A) — only if ws too small for Xb.
// ---------------------------------------------------------------------------
__global__ __launch_bounds__(256) void gemm_fallback(
    const float* __restrict__ Xf,
    const unsigned short* __restrict__ Wd,
    const float* __restrict__ bias,
    float* __restrict__ out)
{
    __shared__ unsigned short As[2][128 * 32];
    __shared__ unsigned short Bs[2][128 * 32];

    const int t = threadIdx.x;
    const int wid = t >> 6, lane = t & 63;
    const int wr = wid >> 1, wc = wid & 1;
    const int m0 = blockIdx.x * 128, n0 = blockIdx.y * 128;
    const int fr = lane & 15, fq = lane >> 4;

    f32x4 acc[4][4] = {};

    const int srow = wid * 16 + (lane >> 2);
    const int scol = (lane & 3) * 8;
    const unsigned short* bsrc0 = Wd + (size_t)(n0 + srow) * IN_DIM + scol;
    const unsigned short* bsrc1 = bsrc0 + (size_t)64 * IN_DIM;
    const int lds_off = wid * 512;

    const int ar = t >> 1;
    const int ak = (t & 1) * 16;
    const float* afp = Xf + (size_t)(m0 + ar) * IN_DIM + ak;
    const int a_lds_off = ar * 32 + ak;

    auto stageB = [&](unsigned short* ldsbase, int kt) {
        __builtin_amdgcn_global_load_lds(
            (const __attribute__((address_space(1))) void*)(bsrc0 + kt * 32),
            (__attribute__((address_space(3))) void*)(ldsbase + lds_off), 16, 0, 0);
        __builtin_amdgcn_global_load_lds(
            (const __attribute__((address_space(1))) void*)(bsrc1 + kt * 32),
            (__attribute__((address_space(3))) void*)(ldsbase + 2048 + lds_off), 16, 0, 0);
    };
    auto writeA = [&](int buf, const f32x4* v) {
        unsigned int w[8];
#pragma unroll
        for (int k = 0; k < 4; ++k) {
            w[2 * k]     = f2bf(v[k][0]) | (f2bf(v[k][1]) << 16);
            w[2 * k + 1] = f2bf(v[k][2]) | (f2bf(v[k][3]) << 16);
        }
        uint4* d = (uint4*)(&As[buf][a_lds_off]);
        d[0] = make_uint4(w[0], w[1], w[2], w[3]);
        d[1] = make_uint4(w[4], w[5], w[6], w[7]);
    };

    stageB(Bs[0], 0);
    {
        f32x4 av[4];
        const f32x4* ap = (const f32x4*)afp;
        av[0] = ap[0]; av[1] = ap[1]; av[2] = ap[2]; av[3] = ap[3];
        writeA(0, av);
    }
    __syncthreads();

    for (int kt = 0; kt < IN_DIM / 32; ++kt) {
        const int cur = kt & 1;
        const bool more = (kt + 1 < IN_DIM / 32);
        f32x4 nv[4];
        if (more) {
            const f32x4* ap = (const f32x4*)(afp + (size_t)(kt + 1) * 32);
            nv[0] = ap[0]; nv[1] = ap[1]; nv[2] = ap[2]; nv[3] = ap[3];
            stageB(Bs[cur ^ 1], kt + 1);
        }
        bf16x8 afrag[4], bfrag[4];
#pragma unroll
        for (int mf = 0; mf < 4; ++mf)
            afrag[mf] = *(const bf16x8*)(&As[cur][(wr * 64 + mf * 16 + fr) * 32 + fq * 8]);
#pragma unroll
        for (int nf = 0; nf < 4; ++nf)
            bfrag[nf] = *(const bf16x8*)(&Bs[cur][(wc * 64 + nf * 16 + fr) * 32 + fq * 8]);
#pragma unroll
        for (int mf = 0; mf < 4; ++mf)
#pragma unroll
            for (int nf = 0; nf < 4; ++nf)
                acc[mf][nf] = __builtin_amdgcn_mfma_f32_16x16x32_bf16(
                    afrag[mf], bfrag[nf], acc[mf][nf], 0, 0, 0);
        if (more) writeA(cur ^ 1, nv);
        __syncthreads();
    }

#pragma unroll
    for (int nf = 0; nf < 4; ++nf) {
        const int col = n0 + wc * 64 + nf * 16 + fr;
        const float bv = bias[col];
#pragma unroll
        for (int mf = 0; mf < 4; ++mf) {
            const int row = m0 + wr * 64 + mf * 16 + fq * 4;
            float* op = out + (size_t)row * OUT_DIM + col;
            op[0 * OUT_DIM] = acc[mf][nf][0] + bv;
            op[1 * OUT_DIM] = acc[mf][nf][1] + bv;
            op[2 * OUT_DIM] = acc[mf][nf][2] + bv;
            op[3 * OUT_DIM] = acc[mf][nf][3] + bv;
        }
    }
}

extern "C" void kernel_launch(void* const* d_in, const int* in_sizes, int n_in,
                              void* d_out, int out_size, void* d_ws, size_t ws_size,
                              hipStream_t stream) {
    const float* x    = (const float*)d_in[0];
    const float* W    = (const float*)d_in[1];
    const float* bias = (const float*)d_in[2];
    const float* dre  = (const float*)d_in[3];
    const float* dimg = (const float*)d_in[4];
    const float* mrow = (const float*)d_in[5];
    float* out = (float*)d_out;

    unsigned short* Wd = (unsigned short*)d_ws;
    const size_t WD_BYTES = (size_t)OUT_DIM * IN_DIM * 2;   // 32 MiB
    const size_t XB_BYTES = (size_t)MROWS * IN_DIM * 2;     // 64 MiB
    unsigned short* Xb = (unsigned short*)((char*)d_ws + WD_BYTES);
    const bool fast = ws_size >= WD_BYTES + XB_BYTES;

    if (fast) {
        const int cvt_blocks = (MROWS * (size_t)IN_DIM / 8) / 256;  // 16384
        prep_kernel<<<OUT_DIM + cvt_blocks, 256, 0, stream>>>(
            x, W, dre, dimg, mrow, Wd, Xb);
        gemm_k32_kernel<<<dim3((MROWS / 128) * (OUT_DIM / 256)), dim3(256), 0, stream>>>(
            Xb, Wd, bias, out);
    } else {
        prep_kernel<<<OUT_DIM, 256, 0, stream>>>(x, W, dre, dimg, mrow, Wd, Wd);
        dim3 grid(MROWS / 128, OUT_DIM / 128);
        gemm_fallback<<<grid, dim3(256), 0, stream>>>(x, Wd, bias, out);
    }
}

// Round 13
// 289.667 us; speedup vs baseline: 1.1371x; 1.1344x over previous
//
#include <hip/hip_runtime.h>
#include <hip/hip_bf16.h>

typedef __attribute__((ext_vector_type(4))) float f32x4;
typedef __attribute__((ext_vector_type(8))) short bf16x8;

#define IN_DIM 4096
#define OUT_DIM 4096
#define MROWS 8192   // B*S = 4*2048
#define NFREQ 8
#define TWO_PI 6.283185307179586f

#define BK 64
#define NT (IN_DIM / BK)        // 64 K-tiles
#define LDS_BUF 32768           // one operand buffer (256x64 bf16)
#define LDS_HALF 16384          // half buffer (128x64 bf16)
#define LDS_B_REGION 65536      // B region base byte

// f32 -> bf16 bits, round-to-nearest-even
__device__ __forceinline__ unsigned int f2bf(float f) {
    union { float f; unsigned int u; } a;
    a.f = f;
    unsigned int u = a.u;
    u += 0x7fffu + ((u >> 16) & 1u);
    return u >> 16;
}

// ---------------------------------------------------------------------------
// Fused prep kernel.
//  blocks [0, 4096):      dora rows — W_dora(bf16) = m*(W+irfft2(pad(delta)))/(||row||+eps)
//  blocks [4096, 20480):  x f32 -> bf16 cvt
// ---------------------------------------------------------------------------
#define ROT_C 0.9999988234517019f
#define ROT_S 0.0015339801862847655f

__global__ __launch_bounds__(256) void prep_kernel(
    const float* __restrict__ x,
    const float* __restrict__ W,
    const float* __restrict__ dre,
    const float* __restrict__ dimg,
    const float* __restrict__ mrow,
    unsigned short* __restrict__ Wd,
    unsigned short* __restrict__ xb)
{
    const int t = threadIdx.x;

    if (blockIdx.x >= OUT_DIM) {
        // ---- cvt branch ----
        const size_t idx = (size_t)(blockIdx.x - OUT_DIM) * 256 + t;
        const f32x4* p = (const f32x4*)(x + idx * 8);
        const f32x4 a = p[0], b = p[1];
        uint4 o;
        o.x = f2bf(a[0]) | (f2bf(a[1]) << 16);
        o.y = f2bf(a[2]) | (f2bf(a[3]) << 16);
        o.z = f2bf(b[0]) | (f2bf(b[1]) << 16);
        o.w = f2bf(b[2]) | (f2bf(b[3]) << 16);
        *(uint4*)(xb + idx * 8) = o;
        return;
    }

    // ---- dora branch ----
    const int o = blockIdx.x;

    float P[NFREQ], Q[NFREQ];
#pragma unroll
    for (int w = 0; w < NFREQ; ++w) { P[w] = 0.f; Q[w] = 0.f; }
#pragma unroll
    for (int h = 0; h < NFREQ; ++h) {
        const float th = (TWO_PI / 4096.0f) * (float)((h * o) & 4095);
        const float sh = __sinf(th), ch = __cosf(th);
#pragma unroll
        for (int w = 0; w < NFREQ; ++w) {
            const float A = 2.0f * dre[h * NFREQ + w];
            const float B = 2.0f * dimg[h * NFREQ + w];
            P[w] += A * ch - B * sh;
            Q[w] += A * sh + B * ch;
        }
    }
#pragma unroll
    for (int w = 0; w < NFREQ; ++w) {
        const float c = (w == 0 ? 1.0f : 2.0f) * (1.0f / 4096.0f);
        P[w] *= c; Q[w] *= c;
    }

    const int i0 = t * 16;
    const f32x4* wrow = (const f32x4*)(W + (size_t)o * IN_DIM + i0);
    float vals[16];
    float ss = 0.0f;

    const float beta0 = (TWO_PI / 4096.0f) * (float)i0;
    float cb = __cosf(beta0), sb = __sinf(beta0);

#pragma unroll
    for (int q = 0; q < 4; ++q) {
        const f32x4 wv = wrow[q];
#pragma unroll
        for (int j = 0; j < 4; ++j) {
            float cw = cb, sw = sb;
            float d = P[0] + P[1] * cw - Q[1] * sw;
#pragma unroll
            for (int w = 2; w < NFREQ; ++w) {
                const float cn = cw * cb - sw * sb;
                sw = sw * cb + cw * sb;
                cw = cn;
                d += P[w] * cw - Q[w] * sw;
            }
            const float v = wv[j] + d;
            vals[q * 4 + j] = v;
            ss += v * v;
            const float cbn = cb * ROT_C - sb * ROT_S;
            sb = sb * ROT_C + cb * ROT_S;
            cb = cbn;
        }
    }

#pragma unroll
    for (int off = 32; off > 0; off >>= 1)
        ss += __shfl_down(ss, off, 64);
    __shared__ float red[4];
    if ((t & 63) == 0) red[t >> 6] = ss;
    __syncthreads();
    const float n2 = red[0] + red[1] + red[2] + red[3];
    const float scale = mrow[o] / (sqrtf(n2) + 1e-8f);

    unsigned int wds[8];
#pragma unroll
    for (int k = 0; k < 8; ++k)
        wds[k] = f2bf(vals[2 * k] * scale) | (f2bf(vals[2 * k + 1] * scale) << 16);
    uint4* dst = (uint4*)(Wd + (size_t)o * IN_DIM + i0);
    dst[0] = make_uint4(wds[0], wds[1], wds[2], wds[3]);
    dst[1] = make_uint4(wds[4], wds[5], wds[6], wds[7]);
}

// ---------------------------------------------------------------------------
// 256x256-tile bf16 GEMM, 16x16x32 MFMA, R7 3-barrier schedule (best
// measured: 237 us gemm, conflicts==0) + paired-tn XCD swizzle for A-panel
// L2 reuse (FETCH 540->295 MB) + lgkm seals before the sealing barriers.
//
// XCD swizzle: xcd = bid&7 gets u = bid>>3 in [0,64); tm = u>>1 (0..31),
// tn = 2*xcd + (u&1) (0..15). Bijective. The ~32 co-resident blocks per
// XCD are (tm 0..15) x (tn pair): each A-panel is read by TWO resident
// blocks (2nd read = L2 hit) and both B-panels (4 MB) fit the XCD L2.
//
// LDS swizzle: slot (row rr, 16B-chunk c) holds global chunk c ^ (rr&7);
// staging pre-swizzles the global source column (linear LDS dest); reads
// XOR the chunk index. Measured 0 bank conflicts.
//
// Schedule per K-tile t (buf b=t&1), 3 barriers/tile:
//   P1: rd a0(8)+bb0(4) | STAGE Bh1(t+1)->b^1 | prio1 MFMA(0,0) prio0
//   P2: rd a1(8)        |                     | prio1 MFMA(1,0) prio0
//       | lgkm0 | SBAR   (seals all A(t) reads)
//   P3: rd bb1(4)       | STAGE Ah0(t+2)->b   | prio1 MFMA(1,1) prio0
//       | lgkm0 | SBAR   (seals all B(t) reads)
//   P4: STAGE Ah1(t+2)->b; STAGE Bh0(t+2)->b  | prio1 MFMA(0,1) prio0
//       | vmcnt(6) | SBAR  (tile boundary)
//
// vmcnt ledger: entering tile t: 6 outstanding (t+1: Ah0,Ah1,Bh0).
//   P1 +2 (Bh1 t+1) = 8; P3 +2 (Ah0 t+2) = 10; P4 +4 = 14. vmcnt(6)
//   drains the oldest 8 = exactly tile t+1's full set. Tail: vmcnt(0).
// ---------------------------------------------------------------------------

#define GLOAD(src, ldsoff)                                                    \
    __builtin_amdgcn_global_load_lds(                                         \
        (const __attribute__((address_space(1))) void*)(src),                 \
        (__attribute__((address_space(3))) void*)(smem + (ldsoff)), 16, 0, 0)

#define SBAR      asm volatile("s_barrier" ::: "memory")
#define WAITLGKM0 asm volatile("s_waitcnt lgkmcnt(0)" ::: "memory")

__device__ __forceinline__ void mfma16(
    f32x4 (&acc)[8][4], const bf16x8 (&af)[4][2], const bf16x8 (&bf)[2][2],
    int MH, int NH)
{
#pragma unroll
    for (int ks = 0; ks < 2; ++ks)
#pragma unroll
        for (int mf = 0; mf < 4; ++mf)
#pragma unroll
            for (int nf = 0; nf < 2; ++nf)
                acc[MH * 4 + mf][NH * 2 + nf] =
                    __builtin_amdgcn_mfma_f32_16x16x32_bf16(
                        af[mf][ks], bf[nf][ks], acc[MH * 4 + mf][NH * 2 + nf],
                        0, 0, 0);
}

__global__ __launch_bounds__(512, 1) void gemm8_kernel(
    const unsigned short* __restrict__ Xb,
    const unsigned short* __restrict__ Wd,
    const float* __restrict__ bias,
    float* __restrict__ out)
{
    __shared__ __align__(1024) unsigned char smem[131072];

    const int tid = threadIdx.x;
    const int wid = tid >> 6, lane = tid & 63;
    const int wr = wid >> 2, wc = wid & 3;        // 2M x 4N waves
    const int fr = lane & 15, fq = lane >> 4;

    // paired-tn XCD swizzle (bijective: 512 blocks, 8 XCDs)
    const int bid = blockIdx.x;
    const int xcd = bid & 7;
    const int u = bid >> 3;                // [0,64) per XCD
    const int tm = u >> 1;                 // 0..31
    const int tn = 2 * xcd + (u & 1);      // 0..15
    const int m0 = tm * 256, n0 = tn * 256;

    // ---- staging coords: pre-swizzled global source, linear LDS dest ----
    const int srr = wid * 16 + (lane >> 3);                 // j=0 row in half
    const int scc = ((lane & 7) ^ (lane >> 3)) * 8;         // swizzled col (elems)
    const unsigned short* aS = Xb + (size_t)(m0 + srr) * IN_DIM + scc;
    const unsigned short* bS = Wd + (size_t)(n0 + srr) * IN_DIM + scc;
    const int sdst = wid * 2048;                            // + j*1024

    // ---- ds_read lane bases (swizzled, per-ks via XOR 64) ----
    const int cbyte = ((fq ^ (fr & 7)) * 16);               // ks=0 chunk byte
    const int aBase0 = (wr * 128 + fr) * 128 + cbyte;       // + b*32768 + mh*8192 + mf*2048
    const int aBase1 = aBase0 ^ 64;                         // ks=1
    const int bBase0 = LDS_B_REGION + (wc * 64 + fr) * 128 + cbyte; // + b*32768 + nh*4096 + nf*2048
    const int bBase1 = bBase0 ^ 64;

    auto STAGE = [&](int buf, int isB, int half, int tt) {
        const unsigned short* s =
            (isB ? bS : aS) + (size_t)half * 128 * IN_DIM + (size_t)tt * BK;
        const int d = buf * LDS_BUF + isB * LDS_B_REGION + half * LDS_HALF + sdst;
        GLOAD(s, d);
        GLOAD(s + 8 * IN_DIM, d + 1024);
    };

    f32x4 acc[8][4] = {};
    bf16x8 a0[4][2], a1[4][2], bb[2][2];

    // ---- prologue: tile0 (4 halves) + tile1 (Ah0, Ah1, Bh0); Bh1(1) comes
    // from P1 of tile 0. Drain tile0's 8 loads: vmcnt(6). ----
    STAGE(0, 0, 0, 0); STAGE(0, 0, 1, 0);
    STAGE(0, 1, 0, 0); STAGE(0, 1, 1, 0);
    STAGE(1, 0, 0, 1); STAGE(1, 0, 1, 1);
    STAGE(1, 1, 0, 1);
    asm volatile("s_waitcnt vmcnt(6)" ::: "memory");
    SBAR;

    for (int t = 0; t < NT; ++t) {
        const int b = t & 1;
        const int bo = b * LDS_BUF;
        const bool st1 = (t + 1 < NT);   // stage Bh1(t+1)
        const bool st2 = (t + 2 < NT);   // stage A(t+2), Bh0(t+2)

        // ---------------- P1: MFMA quad (0,0) ----------------
#pragma unroll
        for (int mf = 0; mf < 4; ++mf) {
            a0[mf][0] = *(const bf16x8*)(smem + bo + aBase0 + mf * 2048);
            a0[mf][1] = *(const bf16x8*)(smem + bo + aBase1 + mf * 2048);
        }
#pragma unroll
        for (int nf = 0; nf < 2; ++nf) {
            bb[nf][0] = *(const bf16x8*)(smem + bo + bBase0 + nf * 2048);
            bb[nf][1] = *(const bf16x8*)(smem + bo + bBase1 + nf * 2048);
        }
        if (st1) STAGE(b ^ 1, 1, 1, t + 1);
        __builtin_amdgcn_s_setprio(1);
        mfma16(acc, a0, bb, 0, 0);
        __builtin_amdgcn_s_setprio(0);

        // ---------------- P2: MFMA quad (1,0) ----------------
#pragma unroll
        for (int mf = 0; mf < 4; ++mf) {
            a1[mf][0] = *(const bf16x8*)(smem + bo + aBase0 + 8192 + mf * 2048);
            a1[mf][1] = *(const bf16x8*)(smem + bo + aBase1 + 8192 + mf * 2048);
        }
        __builtin_amdgcn_s_setprio(1);
        mfma16(acc, a1, bb, 1, 0);
        __builtin_amdgcn_s_setprio(0);
        WAITLGKM0;   // all A(t) fragment reads retired
        SBAR;        // seals A(t) -> P3/P4 A-stages may overwrite buf b A

        // ---------------- P3: MFMA quad (1,1) ----------------
#pragma unroll
        for (int nf = 0; nf < 2; ++nf) {
            bb[nf][0] = *(const bf16x8*)(smem + bo + bBase0 + 4096 + nf * 2048);
            bb[nf][1] = *(const bf16x8*)(smem + bo + bBase1 + 4096 + nf * 2048);
        }
        if (st2) STAGE(b, 0, 0, t + 2);
        __builtin_amdgcn_s_setprio(1);
        mfma16(acc, a1, bb, 1, 1);
        __builtin_amdgcn_s_setprio(0);
        WAITLGKM0;   // all B(t) fragment reads retired
        SBAR;        // seals B(t) -> P4 B-stage may overwrite buf b B

        // ---------------- P4: MFMA quad (0,1) ----------------
        if (st2) { STAGE(b, 0, 1, t + 2); STAGE(b, 1, 0, t + 2); }
        __builtin_amdgcn_s_setprio(1);
        mfma16(acc, a0, bb, 0, 1);
        __builtin_amdgcn_s_setprio(0);
        if (st2) {
            asm volatile("s_waitcnt vmcnt(6)" ::: "memory");
        } else {
            asm volatile("s_waitcnt vmcnt(0)" ::: "memory");
        }
        SBAR;   // tile boundary
    }

    // ---- epilogue: bias add + f32 store ----
#pragma unroll
    for (int nf = 0; nf < 4; ++nf) {
        const int col = n0 + wc * 64 + nf * 16 + fr;
        const float bv = bias[col];
#pragma unroll
        for (int mf = 0; mf < 8; ++mf) {
            const int row = m0 + wr * 128 + mf * 16 + fq * 4;
            float* op = out + (size_t)row * OUT_DIM + col;
            op[0 * OUT_DIM] = acc[mf][nf][0] + bv;
            op[1 * OUT_DIM] = acc[mf][nf][1] + bv;
            op[2 * OUT_DIM] = acc[mf][nf][2] + bv;
            op[3 * OUT_DIM] = acc[mf][nf][3] + bv;
        }
    }
}

// ---------------------------------------------------------------------------
// Fallback GEMM (128x128, reg-staged f32 A) — only if ws too small for Xb.
// ---------------------------------------------------------------------------
__global__ __launch_bounds__(256) void gemm_fallback(
    const float* __restrict__ Xf,
    const unsigned short* __restrict__ Wd,
    const float* __restrict__ bias,
    float* __restrict__ out)
{
    __shared__ unsigned short As[2][128 * 32];
    __shared__ unsigned short Bs[2][128 * 32];

    const int t = threadIdx.x;
    const int wid = t >> 6, lane = t & 63;
    const int wr = wid >> 1, wc = wid & 1;
    const int m0 = blockIdx.x * 128, n0 = blockIdx.y * 128;
    const int fr = lane & 15, fq = lane >> 4;

    f32x4 acc[4][4] = {};

    const int srow = wid * 16 + (lane >> 2);
    const int scol = (lane & 3) * 8;
    const unsigned short* bsrc0 = Wd + (size_t)(n0 + srow) * IN_DIM + scol;
    const unsigned short* bsrc1 = bsrc0 + (size_t)64 * IN_DIM;
    const int lds_off = wid * 512;

    const int ar = t >> 1;
    const int ak = (t & 1) * 16;
    const float* afp = Xf + (size_t)(m0 + ar) * IN_DIM + ak;
    const int a_lds_off = ar * 32 + ak;

    auto stageB = [&](unsigned short* ldsbase, int kt) {
        __builtin_amdgcn_global_load_lds(
            (const __attribute__((address_space(1))) void*)(bsrc0 + kt * 32),
            (__attribute__((address_space(3))) void*)(ldsbase + lds_off), 16, 0, 0);
        __builtin_amdgcn_global_load_lds(
            (const __attribute__((address_space(1))) void*)(bsrc1 + kt * 32),
            (__attribute__((address_space(3))) void*)(ldsbase + 2048 + lds_off), 16, 0, 0);
    };
    auto writeA = [&](int buf, const f32x4* v) {
        unsigned int w[8];
#pragma unroll
        for (int k = 0; k < 4; ++k) {
            w[2 * k]     = f2bf(v[k][0]) | (f2bf(v[k][1]) << 16);
            w[2 * k + 1] = f2bf(v[k][2]) | (f2bf(v[k][3]) << 16);
        }
        uint4* d = (uint4*)(&As[buf][a_lds_off]);
        d[0] = make_uint4(w[0], w[1], w[2], w[3]);
        d[1] = make_uint4(w[4], w[5], w[6], w[7]);
    };

    stageB(Bs[0], 0);
    {
        f32x4 av[4];
        const f32x4* ap = (const f32x4*)afp;
        av[0] = ap[0]; av[1] = ap[1]; av[2] = ap[2]; av[3] = ap[3];
        writeA(0, av);
    }
    __syncthreads();

    for (int kt = 0; kt < IN_DIM / 32; ++kt) {
        const int cur = kt & 1;
        const bool more = (kt + 1 < IN_DIM / 32);
        f32x4 nv[4];
        if (more) {
            const f32x4* ap = (const f32x4*)(afp + (size_t)(kt + 1) * 32);
            nv[0] = ap[0]; nv[1] = ap[1]; nv[2] = ap[2]; nv[3] = ap[3];
            stageB(Bs[cur ^ 1], kt + 1);
        }
        bf16x8 afrag[4], bfrag[4];
#pragma unroll
        for (int mf = 0; mf < 4; ++mf)
            afrag[mf] = *(const bf16x8*)(&As[cur][(wr * 64 + mf * 16 + fr) * 32 + fq * 8]);
#pragma unroll
        for (int nf = 0; nf < 4; ++nf)
            bfrag[nf] = *(const bf16x8*)(&Bs[cur][(wc * 64 + nf * 16 + fr) * 32 + fq * 8]);
#pragma unroll
        for (int mf = 0; mf < 4; ++mf)
#pragma unroll
            for (int nf = 0; nf < 4; ++nf)
                acc[mf][nf] = __builtin_amdgcn_mfma_f32_16x16x32_bf16(
                    afrag[mf], bfrag[nf], acc[mf][nf], 0, 0, 0);
        if (more) writeA(cur ^ 1, nv);
        __syncthreads();
    }

#pragma unroll
    for (int nf = 0; nf < 4; ++nf) {
        const int col = n0 + wc * 64 + nf * 16 + fr;
        const float bv = bias[col];
#pragma unroll
        for (int mf = 0; mf < 4; ++mf) {
            const int row = m0 + wr * 64 + mf * 16 + fq * 4;
            float* op = out + (size_t)row * OUT_DIM + col;
            op[0 * OUT_DIM] = acc[mf][nf][0] + bv;
            op[1 * OUT_DIM] = acc[mf][nf][1] + bv;
            op[2 * OUT_DIM] = acc[mf][nf][2] + bv;
            op[3 * OUT_DIM] = acc[mf][nf][3] + bv;
        }
    }
}

extern "C" void kernel_launch(void* const* d_in, const int* in_sizes, int n_in,
                              void* d_out, int out_size, void* d_ws, size_t ws_size,
                              hipStream_t stream) {
    const float* x    = (const float*)d_in[0];
    const float* W    = (const float*)d_in[1];
    const float* bias = (const float*)d_in[2];
    const float* dre  = (const float*)d_in[3];
    const float* dimg = (const float*)d_in[4];
    const float* mrow = (const float*)d_in[5];
    float* out = (float*)d_out;

    unsigned short* Wd = (unsigned short*)d_ws;
    const size_t WD_BYTES = (size_t)OUT_DIM * IN_DIM * 2;   // 32 MiB
    const size_t XB_BYTES = (size_t)MROWS * IN_DIM * 2;     // 64 MiB
    unsigned short* Xb = (unsigned short*)((char*)d_ws + WD_BYTES);
    const bool fast = ws_size >= WD_BYTES + XB_BYTES;

    if (fast) {
        const int cvt_blocks = (MROWS * (size_t)IN_DIM / 8) / 256;  // 16384
        prep_kernel<<<OUT_DIM + cvt_blocks, 256, 0, stream>>>(
            x, W, dre, dimg, mrow, Wd, Xb);
        gemm8_kernel<<<dim3((MROWS / 256) * (OUT_DIM / 256)), dim3(512), 0, stream>>>(
            Xb, Wd, bias, out);
    } else {
        prep_kernel<<<OUT_DIM, 256, 0, stream>>>(x, W, dre, dimg, mrow, Wd, Wd);
        dim3 grid(MROWS / 128, OUT_DIM / 128);
        gemm_fallback<<<grid, dim3(256), 0, stream>>>(x, Wd, bias, out);
    }
}